// Round 1
// baseline (1307.687 us; speedup 1.0000x reference)
//
#include <hip/hip_runtime.h>
#include <hip/hip_bf16.h>
#include <math.h>

#define DEVI __device__ __forceinline__

typedef unsigned short u16;
typedef __attribute__((ext_vector_type(8))) __bf16 bf16x8;
typedef __attribute__((ext_vector_type(4))) float f32x4;
typedef __attribute__((ext_vector_type(8))) unsigned short u16x8;
typedef __attribute__((ext_vector_type(4))) unsigned short u16x4;
typedef __attribute__((ext_vector_type(4))) unsigned int u32x4;

DEVI u16 f2bf(float f) {
  unsigned u = __builtin_bit_cast(unsigned, f);
  u += 0x7fffu + ((u >> 16) & 1u);   // RNE
  return (u16)(u >> 16);
}

DEVI f32x4 mfma_bf16(bf16x8 a, bf16x8 b, f32x4 c) {
  return __builtin_amdgcn_mfma_f32_16x16x32_bf16(a, b, c, 0, 0, 0);
}

// ---------------------------------------------------------------- reductions
__global__ void sumsq_k(const float* __restrict__ v, int n4, float* __restrict__ out)
{
  float s = 0.f;
  const int stride = gridDim.x * blockDim.x;
  for (int i = blockIdx.x * blockDim.x + threadIdx.x; i < n4; i += stride) {
    f32x4 x = *(const f32x4*)(v + (size_t)i * 4);
    s += x.x * x.x + x.y * x.y + x.z * x.z + x.w * x.w;
  }
#pragma unroll
  for (int off = 32; off > 0; off >>= 1) s += __shfl_down(s, off);
  __shared__ float part[4];
  if ((threadIdx.x & 63) == 0) part[threadIdx.x >> 6] = s;
  __syncthreads();
  if (threadIdx.x == 0) atomicAdd(out, part[0] + part[1] + part[2] + part[3]);
}

__global__ void wconv_k(const float* __restrict__ v, const float* __restrict__ g,
                        const float* __restrict__ ss, u16* __restrict__ w, int n4)
{
  const int i = blockIdx.x * blockDim.x + threadIdx.x;
  if (i >= n4) return;
  const float sc = g[0] / sqrtf(ss[0]);   // weight-norm scale (==1.0 at init)
  f32x4 x = *(const f32x4*)(v + (size_t)i * 4);
  u16x4 o;
  o[0] = f2bf(x.x * sc); o[1] = f2bf(x.y * sc);
  o[2] = f2bf(x.z * sc); o[3] = f2bf(x.w * sc);
  *(u16x4*)(w + (size_t)i * 4) = o;
}

// tgt f32 -> bf16 into left half of cat [16384][2048]
__global__ void catleft_k(const float* __restrict__ tgt, u16* __restrict__ cat)
{
  const size_t e = (size_t)(blockIdx.x * blockDim.x + threadIdx.x) * 4;
  const int row = (int)(e >> 10), c = (int)(e & 1023);
  f32x4 x = *(const f32x4*)(tgt + e);
  u16x4 o;
  o[0] = f2bf(x.x); o[1] = f2bf(x.y); o[2] = f2bf(x.z); o[3] = f2bf(x.w);
  *(u16x4*)&cat[(size_t)row * 2048 + c] = o;
}

// ---------------------------------------------------------------- GEMM (C = A @ B^T + bias, optional row mask)
// A: [M][lda] f32 or bf16; B: [N][K] bf16; grid = (N/128, M/128); 256 threads.
template<bool A_F32, bool OUT_BF16, bool HAS_MASK>
__global__ void gemm_bt(const void* __restrict__ Ap, const u16* __restrict__ Bp,
                        const float* __restrict__ bias, const float* __restrict__ rowmask,
                        void* __restrict__ Cp, int K, int lda, int ldc)
{
  __shared__ u16 As[128][40];   // +8 pad breaks bank stride
  __shared__ u16 Bs[128][40];
  const int tid = threadIdx.x;
  const int wave = tid >> 6, lane = tid & 63;
  const int wm = (wave >> 1) * 64, wn = (wave & 1) * 64;
  const int l = lane & 15, q = lane >> 4;
  const int m0 = blockIdx.y * 128, n0 = blockIdx.x * 128;
  const int sr = tid >> 1, sk = (tid & 1) * 16;

  const f32x4 zero = {0.f, 0.f, 0.f, 0.f};
  f32x4 acc[4][4];
#pragma unroll
  for (int i = 0; i < 4; i++)
#pragma unroll
    for (int j = 0; j < 4; j++) acc[i][j] = zero;

  const u16* brow = Bp + (size_t)(n0 + sr) * K + sk;

  for (int k0 = 0; k0 < K; k0 += 32) {
    __syncthreads();
    if constexpr (A_F32) {
      const float* a = (const float*)Ap + (size_t)(m0 + sr) * lda + k0 + sk;
      f32x4 v0 = *(const f32x4*)a;
      f32x4 v1 = *(const f32x4*)(a + 4);
      f32x4 v2 = *(const f32x4*)(a + 8);
      f32x4 v3 = *(const f32x4*)(a + 12);
      u16x8 o0, o1;
      o0[0] = f2bf(v0.x); o0[1] = f2bf(v0.y); o0[2] = f2bf(v0.z); o0[3] = f2bf(v0.w);
      o0[4] = f2bf(v1.x); o0[5] = f2bf(v1.y); o0[6] = f2bf(v1.z); o0[7] = f2bf(v1.w);
      o1[0] = f2bf(v2.x); o1[1] = f2bf(v2.y); o1[2] = f2bf(v2.z); o1[3] = f2bf(v2.w);
      o1[4] = f2bf(v3.x); o1[5] = f2bf(v3.y); o1[6] = f2bf(v3.z); o1[7] = f2bf(v3.w);
      *(u16x8*)&As[sr][sk] = o0;
      *(u16x8*)&As[sr][sk + 8] = o1;
    } else {
      const u16* a = (const u16*)Ap + (size_t)(m0 + sr) * lda + k0 + sk;
      *(u16x8*)&As[sr][sk] = *(const u16x8*)a;
      *(u16x8*)&As[sr][sk + 8] = *(const u16x8*)(a + 8);
    }
    {
      const u16* bsrc = brow + k0;
      *(u16x8*)&Bs[sr][sk] = *(const u16x8*)bsrc;
      *(u16x8*)&Bs[sr][sk + 8] = *(const u16x8*)(bsrc + 8);
    }
    __syncthreads();

    bf16x8 af[4], bfr[4];
#pragma unroll
    for (int i = 0; i < 4; i++) af[i] = *(const bf16x8*)&As[wm + i * 16 + l][q * 8];
#pragma unroll
    for (int j = 0; j < 4; j++) bfr[j] = *(const bf16x8*)&Bs[wn + j * 16 + l][q * 8];
#pragma unroll
    for (int i = 0; i < 4; i++)
#pragma unroll
      for (int j = 0; j < 4; j++)
        acc[i][j] = mfma_bf16(af[i], bfr[j], acc[i][j]);
  }

  float mk[4][4];
  if constexpr (HAS_MASK) {
#pragma unroll
    for (int i = 0; i < 4; i++)
#pragma unroll
      for (int r = 0; r < 4; r++)
        mk[i][r] = rowmask[m0 + wm + i * 16 + q * 4 + r];
  }
#pragma unroll
  for (int j = 0; j < 4; j++) {
    const int col = n0 + wn + j * 16 + l;
    const float bv = bias[col];
#pragma unroll
    for (int i = 0; i < 4; i++) {
#pragma unroll
      for (int r = 0; r < 4; r++) {
        float v = acc[i][j][r] + bv;
        if constexpr (HAS_MASK) v *= mk[i][r];
        const size_t off = (size_t)(m0 + wm + i * 16 + q * 4 + r) * ldc + col;
        if constexpr (OUT_BF16) ((u16*)Cp)[off] = f2bf(v);
        else                    ((float*)Cp)[off] = v;
      }
    }
  }
}

// ---------------------------------------------------------------- V transpose: src_trans val half -> vt [B*H][128][1024]
__global__ void tpose_k(const u16* __restrict__ st, u16* __restrict__ vt)
{
  const int s0 = blockIdx.x * 64, d0 = blockIdx.y * 64, bh = blockIdx.z;
  const int b = bh >> 3, h = bh & 7;
  __shared__ unsigned tile[64][33];   // u32 = 2 bf16 (s-pair); odd stride -> 2-way max
  const int tid = threadIdx.x;
  {
    const int k = tid & 7, sp = tid >> 3;  // sp: 0..31 (s-pairs), k: 0..7 (d octets)
    const u16* src = st + (size_t)(b * 1024 + s0 + sp * 2) * 2048 + 1024 + h * 128 + d0 + k * 8;
    u16x8 r0 = *(const u16x8*)src;
    u16x8 r1 = *(const u16x8*)(src + 2048);
#pragma unroll
    for (int j = 0; j < 8; j++)
      tile[k * 8 + j][sp] = (unsigned)r0[j] | ((unsigned)r1[j] << 16);
  }
  __syncthreads();
  {
    const int d = tid >> 2, m = tid & 3;
    u32x4 w0, w1;
#pragma unroll
    for (int i = 0; i < 4; i++) w0[i] = tile[d][m * 8 + i];
#pragma unroll
    for (int i = 0; i < 4; i++) w1[i] = tile[d][m * 8 + 4 + i];
    u16* dst = vt + (size_t)(bh * 128 + d0 + d) * 1024 + s0 + m * 16;
    *(u32x4*)dst = w0;
    *(u32x4*)(dst + 8) = w1;
  }
}

// ---------------------------------------------------------------- attention
// grid (T/16, H, B), 256 threads (4 waves; wave w owns s-range [w*256, w*256+256))
__global__ __launch_bounds__(256) void attn_k(
    const u16* __restrict__ st,    // src_trans [B*S][2048] (key cols 0..1023)
    const u16* __restrict__ vt,    // [B*H][128][1024] (V^T)
    const u16* __restrict__ qb,    // tgt_trans [B*T][1024]
    const float* __restrict__ smask,
    u16* __restrict__ cat)         // [B*T][2048], writes cols 1024..2047
{
  const int tt = blockIdx.x, h = blockIdx.y, b = blockIdx.z;
  const int tid = threadIdx.x, wave = tid >> 6, lane = tid & 63;
  const int l = lane & 15, q = lane >> 4;

  __shared__ u16 qt[16][136];
  __shared__ float mS[1024];
  __shared__ u16 p[16][1032];
  __shared__ float red[2][4][16];

  {
    const int i = tid >> 4, d8 = (tid & 15) * 8;
    *(u16x8*)&qt[i][d8] =
        *(const u16x8*)&qb[(size_t)(b * 512 + tt * 16 + i) * 1024 + h * 128 + d8];
    *(f32x4*)&mS[tid * 4] = *(const f32x4*)&smask[b * 1024 + tid * 4];
  }
  __syncthreads();

  const int sbase = wave * 256;
  const f32x4 zero = {0.f, 0.f, 0.f, 0.f};
  f32x4 acc[16];
#pragma unroll
  for (int nt = 0; nt < 16; nt++) acc[nt] = zero;

  // --- QK^T (B-frags gathered from global; wave covers full 64B lines)
  const u16* kb = st + (size_t)(b * 1024) * 2048 + h * 128;
#pragma unroll
  for (int kk = 0; kk < 4; kk++) {
    bf16x8 a4 = *(const bf16x8*)&qt[l][kk * 32 + q * 8];
#pragma unroll
    for (int nt = 0; nt < 16; nt++) {
      bf16x8 b4 = *(const bf16x8*)&kb[(size_t)(sbase + nt * 16 + l) * 2048 + kk * 32 + q * 8];
      acc[nt] = mfma_bf16(a4, b4, acc[nt]);
    }
  }

  // --- softmax over full S (mask + scale, cross-lane + cross-wave reduce)
  const float scale = 0.08838834764831845f;  // 1/sqrt(128)
  float msk[16];
#pragma unroll
  for (int nt = 0; nt < 16; nt++) msk[nt] = mS[sbase + nt * 16 + l];

  float mloc[4] = {-3e38f, -3e38f, -3e38f, -3e38f};
#pragma unroll
  for (int nt = 0; nt < 16; nt++) {
#pragma unroll
    for (int r = 0; r < 4; r++) {
      float v = acc[nt][r] * scale;
      v = (msk[nt] == 0.f) ? -3e38f : v;
      acc[nt][r] = v;
      mloc[r] = fmaxf(mloc[r], v);
    }
  }
#pragma unroll
  for (int off = 1; off < 16; off <<= 1)
#pragma unroll
    for (int r = 0; r < 4; r++) mloc[r] = fmaxf(mloc[r], __shfl_xor(mloc[r], off));
  if (l == 0) {
#pragma unroll
    for (int r = 0; r < 4; r++) red[0][wave][q * 4 + r] = mloc[r];
  }
  __syncthreads();
  float rmax[4];
#pragma unroll
  for (int r = 0; r < 4; r++) {
    const int row = q * 4 + r;
    rmax[r] = fmaxf(fmaxf(red[0][0][row], red[0][1][row]),
                    fmaxf(red[0][2][row], red[0][3][row]));
  }
  float sloc[4] = {0.f, 0.f, 0.f, 0.f};
#pragma unroll
  for (int nt = 0; nt < 16; nt++) {
#pragma unroll
    for (int r = 0; r < 4; r++) {
      float e = __expf(acc[nt][r] - rmax[r]);
      acc[nt][r] = e;
      sloc[r] += e;
    }
  }
#pragma unroll
  for (int off = 1; off < 16; off <<= 1)
#pragma unroll
    for (int r = 0; r < 4; r++) sloc[r] += __shfl_xor(sloc[r], off);
  if (l == 0) {
#pragma unroll
    for (int r = 0; r < 4; r++) red[1][wave][q * 4 + r] = sloc[r];
  }
  __syncthreads();
  float rinv[4];
#pragma unroll
  for (int r = 0; r < 4; r++) {
    const int row = q * 4 + r;
    rinv[r] = 1.f / (red[1][0][row] + red[1][1][row] + red[1][2][row] + red[1][3][row]);
  }
#pragma unroll
  for (int nt = 0; nt < 16; nt++) {
#pragma unroll
    for (int r = 0; r < 4; r++)
      p[q * 4 + r][sbase + nt * 16 + l] = f2bf(acc[nt][r] * rinv[r]);
  }
  __syncthreads();

  // --- PV (A from LDS P, B-frags from V^T in global: contiguous along s)
  f32x4 o0 = zero, o1 = zero;
  const u16* vb = vt + (size_t)(b * 8 + h) * 128 * 1024 + (size_t)(wave * 32) * 1024;
#pragma unroll 4
  for (int c = 0; c < 32; c++) {
    bf16x8 a4 = *(const bf16x8*)&p[l][c * 32 + q * 8];
    bf16x8 b0 = *(const bf16x8*)&vb[(size_t)l * 1024 + c * 32 + q * 8];
    bf16x8 b1 = *(const bf16x8*)&vb[(size_t)(l + 16) * 1024 + c * 32 + q * 8];
    o0 = mfma_bf16(a4, b0, o0);
    o1 = mfma_bf16(a4, b1, o1);
  }
  u16* ob = cat + (size_t)(b * 512 + tt * 16 + q * 4) * 2048 + 1024 + h * 128 + wave * 32 + l;
#pragma unroll
  for (int r = 0; r < 4; r++) {
    ob[(size_t)r * 2048] = f2bf(o0[r]);
    ob[(size_t)r * 2048 + 16] = f2bf(o1[r]);
  }
}

// ---------------------------------------------------------------- launcher
extern "C" void kernel_launch(void* const* d_in, const int* in_sizes, int n_in,
                              void* d_out, int out_size, void* d_ws, size_t ws_size,
                              hipStream_t stream)
{
  (void)in_sizes; (void)n_in; (void)out_size; (void)ws_size;
  const float* src      = (const float*)d_in[0];
  const float* tgtf     = (const float*)d_in[1];
  const float* src_mask = (const float*)d_in[2];
  const float* tgt_mask = (const float*)d_in[3];
  const float* v_src = (const float*)d_in[4];
  const float* g_src = (const float*)d_in[5];
  const float* b_src = (const float*)d_in[6];
  const float* v_tgt = (const float*)d_in[7];
  const float* g_tgt = (const float*)d_in[8];
  const float* b_tgt = (const float*)d_in[9];
  const float* v_out = (const float*)d_in[10];
  const float* g_out = (const float*)d_in[11];
  const float* b_out = (const float*)d_in[12];

  char* w = (char*)d_ws;
  float* sumsq = (float*)w;
  size_t off = 256;
  u16* w_src = (u16*)(w + off); off += (size_t)2048 * 1024 * 2;
  u16* w_tgt = (u16*)(w + off); off += (size_t)1024 * 1024 * 2;
  u16* w_out = (u16*)(w + off); off += (size_t)1024 * 2048 * 2;
  u16* st    = (u16*)(w + off); off += (size_t)32768 * 2048 * 2;   // src_trans bf16
  u16* qb    = (u16*)(w + off); off += (size_t)16384 * 1024 * 2;   // tgt_trans bf16
  u16* vt    = (u16*)(w + off); off += (size_t)256 * 128 * 1024 * 2; // V^T bf16
  u16* cat   = (u16*)(w + off); off += (size_t)16384 * 2048 * 2;   // [tgt | tgt_update] bf16

  hipMemsetAsync(sumsq, 0, 256, stream);
  sumsq_k<<<256, 256, 0, stream>>>(v_src, 2048 * 1024 / 4, sumsq + 0);
  sumsq_k<<<256, 256, 0, stream>>>(v_tgt, 1024 * 1024 / 4, sumsq + 1);
  sumsq_k<<<256, 256, 0, stream>>>(v_out, 1024 * 2048 / 4, sumsq + 2);
  wconv_k<<<2048, 256, 0, stream>>>(v_src, g_src, sumsq + 0, w_src, 2048 * 1024 / 4);
  wconv_k<<<1024, 256, 0, stream>>>(v_tgt, g_tgt, sumsq + 1, w_tgt, 1024 * 1024 / 4);
  wconv_k<<<2048, 256, 0, stream>>>(v_out, g_out, sumsq + 2, w_out, 1024 * 2048 / 4);
  catleft_k<<<16384, 256, 0, stream>>>(tgtf, cat);

  // src_trans = (src @ W_src^T + b_src) * src_mask   [32768 x 2048]
  gemm_bt<true, true, true><<<dim3(16, 256), 256, 0, stream>>>(
      (const void*)src, w_src, b_src, src_mask, (void*)st, 1024, 1024, 2048);
  // tgt_trans = (tgt @ W_tgt^T + b_tgt) * tgt_mask   [16384 x 1024]
  gemm_bt<true, true, true><<<dim3(8, 128), 256, 0, stream>>>(
      (const void*)tgtf, w_tgt, b_tgt, tgt_mask, (void*)qb, 1024, 1024, 1024);
  // V^T
  tpose_k<<<dim3(16, 2, 256), 256, 0, stream>>>(st, vt);
  // attention -> cat[:, 1024:]
  attn_k<<<dim3(32, 8, 32), 256, 0, stream>>>(st, vt, qb, src_mask, cat);
  // out = cat @ W_out^T + b_out   [16384 x 1024] f32
  gemm_bt<false, false, false><<<dim3(8, 128), 256, 0, stream>>>(
      (const void*)cat, w_out, b_out, nullptr, d_out, 2048, 2048, 1024);
}

// Round 2
// 963.022 us; speedup vs baseline: 1.3579x; 1.3579x over previous
//
#include <hip/hip_runtime.h>
#include <hip/hip_bf16.h>
#include <math.h>

#define DEVI __device__ __forceinline__

typedef unsigned short u16;
typedef __attribute__((ext_vector_type(8))) __bf16 bf16x8;
typedef __attribute__((ext_vector_type(4))) float f32x4;
typedef __attribute__((ext_vector_type(8))) unsigned short u16x8;
typedef __attribute__((ext_vector_type(4))) unsigned short u16x4;
typedef __attribute__((ext_vector_type(4))) unsigned int u32x4;

typedef __attribute__((address_space(1))) void gvoid;
typedef __attribute__((address_space(3))) void lvoid;

DEVI u16 f2bf(float f) {
  unsigned u = __builtin_bit_cast(unsigned, f);
  u += 0x7fffu + ((u >> 16) & 1u);   // RNE
  return (u16)(u >> 16);
}

DEVI f32x4 mfma_bf16(bf16x8 a, bf16x8 b, f32x4 c) {
  return __builtin_amdgcn_mfma_f32_16x16x32_bf16(a, b, c, 0, 0, 0);
}

// async global->LDS, 16B per lane; LDS dest = wave-uniform base + lane*16
DEVI void g2l16(const void* g, const void* l) {
  __builtin_amdgcn_global_load_lds((gvoid*)(size_t)g,
                                   (lvoid*)(unsigned)(size_t)l, 16, 0, 0);
}

// ---------------------------------------------------------------- small kernels
__global__ void sumsq_k(const float* __restrict__ v, int n4, float* __restrict__ out)
{
  float s = 0.f;
  const int stride = gridDim.x * blockDim.x;
  for (int i = blockIdx.x * blockDim.x + threadIdx.x; i < n4; i += stride) {
    f32x4 x = *(const f32x4*)(v + (size_t)i * 4);
    s += x.x * x.x + x.y * x.y + x.z * x.z + x.w * x.w;
  }
#pragma unroll
  for (int off = 32; off > 0; off >>= 1) s += __shfl_down(s, off);
  __shared__ float part[4];
  if ((threadIdx.x & 63) == 0) part[threadIdx.x >> 6] = s;
  __syncthreads();
  if (threadIdx.x == 0) atomicAdd(out, part[0] + part[1] + part[2] + part[3]);
}

__global__ void wconv_k(const float* __restrict__ v, const float* __restrict__ g,
                        const float* __restrict__ ss, u16* __restrict__ w, int n4)
{
  const int i = blockIdx.x * blockDim.x + threadIdx.x;
  if (i >= n4) return;
  const float sc = g[0] / sqrtf(ss[0]);   // weight-norm scale
  f32x4 x = *(const f32x4*)(v + (size_t)i * 4);
  u16x4 o;
  o[0] = f2bf(x.x * sc); o[1] = f2bf(x.y * sc);
  o[2] = f2bf(x.z * sc); o[3] = f2bf(x.w * sc);
  *(u16x4*)(w + (size_t)i * 4) = o;
}

// plain f32 -> bf16 convert (for src)
__global__ void cvt_k(const float* __restrict__ x, u16* __restrict__ y)
{
  const size_t i = (size_t)(blockIdx.x * blockDim.x + threadIdx.x) * 4;
  f32x4 v = *(const f32x4*)(x + i);
  u16x4 o;
  o[0] = f2bf(v.x); o[1] = f2bf(v.y); o[2] = f2bf(v.z); o[3] = f2bf(v.w);
  *(u16x4*)(y + i) = o;
}

// tgt f32 -> bf16 into left half of cat [16384][2048]
__global__ void catleft_k(const float* __restrict__ tgt, u16* __restrict__ cat)
{
  const size_t e = (size_t)(blockIdx.x * blockDim.x + threadIdx.x) * 4;
  const int row = (int)(e >> 10), c = (int)(e & 1023);
  f32x4 x = *(const f32x4*)(tgt + e);
  u16x4 o;
  o[0] = f2bf(x.x); o[1] = f2bf(x.y); o[2] = f2bf(x.z); o[3] = f2bf(x.w);
  *(u16x4*)&cat[(size_t)row * 2048 + c] = o;
}

// ---------------------------------------------------------------- GEMM (C = A @ B^T + bias, optional row mask)
// A: [M][lda] bf16; B: [N][K] bf16; grid = (N/128, M/128); 256 threads. m97 structure.
template<bool OUT_BF16, bool HAS_MASK>
__global__ __launch_bounds__(256) void gemm_bt(
    const u16* __restrict__ Ap, const u16* __restrict__ Bp,
    const float* __restrict__ bias, const float* __restrict__ rowmask,
    void* __restrict__ Cp, int K, int lda, int ldc)
{
  __shared__ u16 As[128 * 32];   // unpadded: required by global_load_lds
  __shared__ u16 Bs[128 * 32];
  const int tid = threadIdx.x;
  const int wave = tid >> 6, lane = tid & 63;
  const int wm = (wave >> 1) * 64, wn = (wave & 1) * 64;
  const int l = lane & 15, q = lane >> 4;
  const int m0 = blockIdx.y * 128, n0 = blockIdx.x * 128;
  // staging: inst i = wave*2+j covers rows [i*16, i*16+16); lane -> row i*16+(lane>>2), col (lane&3)*8
  const int sr0 = wave * 32 + (lane >> 2);
  const int skc = (lane & 3) * 8;

  const f32x4 zero = {0.f, 0.f, 0.f, 0.f};
  f32x4 acc[4][4];
#pragma unroll
  for (int i = 0; i < 4; i++)
#pragma unroll
    for (int j = 0; j < 4; j++) acc[i][j] = zero;

  for (int k0 = 0; k0 < K; k0 += 32) {
    __syncthreads();
    g2l16(Ap + (size_t)(m0 + sr0) * lda + k0 + skc,      (const char*)As + (wave * 2 + 0) * 1024);
    g2l16(Ap + (size_t)(m0 + sr0 + 16) * lda + k0 + skc, (const char*)As + (wave * 2 + 1) * 1024);
    g2l16(Bp + (size_t)(n0 + sr0) * K + k0 + skc,        (const char*)Bs + (wave * 2 + 0) * 1024);
    g2l16(Bp + (size_t)(n0 + sr0 + 16) * K + k0 + skc,   (const char*)Bs + (wave * 2 + 1) * 1024);
    __syncthreads();

    bf16x8 af[4], bfr[4];
#pragma unroll
    for (int i = 0; i < 4; i++) af[i] = *(const bf16x8*)&As[(wm + i * 16 + l) * 32 + q * 8];
#pragma unroll
    for (int j = 0; j < 4; j++) bfr[j] = *(const bf16x8*)&Bs[(wn + j * 16 + l) * 32 + q * 8];
#pragma unroll
    for (int i = 0; i < 4; i++)
#pragma unroll
      for (int j = 0; j < 4; j++)
        acc[i][j] = mfma_bf16(af[i], bfr[j], acc[i][j]);
  }

  float mk[4][4];
  if constexpr (HAS_MASK) {
#pragma unroll
    for (int i = 0; i < 4; i++)
#pragma unroll
      for (int r = 0; r < 4; r++)
        mk[i][r] = rowmask[m0 + wm + i * 16 + q * 4 + r];
  }
#pragma unroll
  for (int j = 0; j < 4; j++) {
    const int col = n0 + wn + j * 16 + l;
    const float bv = bias[col];
#pragma unroll
    for (int i = 0; i < 4; i++) {
#pragma unroll
      for (int r = 0; r < 4; r++) {
        float v = acc[i][j][r] + bv;
        if constexpr (HAS_MASK) v *= mk[i][r];
        const size_t off = (size_t)(m0 + wm + i * 16 + q * 4 + r) * ldc + col;
        if constexpr (OUT_BF16) ((u16*)Cp)[off] = f2bf(v);
        else                    ((float*)Cp)[off] = v;
      }
    }
  }
}

// ---------------------------------------------------------------- V transpose: src_trans val half -> vt [B*H][128][1024]
__global__ void tpose_k(const u16* __restrict__ st, u16* __restrict__ vt)
{
  const int s0 = blockIdx.x * 64, d0 = blockIdx.y * 64, bh = blockIdx.z;
  const int b = bh >> 3, h = bh & 7;
  __shared__ unsigned tile[64][33];
  const int tid = threadIdx.x;
  {
    const int k = tid & 7, sp = tid >> 3;
    const u16* src = st + (size_t)(b * 1024 + s0 + sp * 2) * 2048 + 1024 + h * 128 + d0 + k * 8;
    u16x8 r0 = *(const u16x8*)src;
    u16x8 r1 = *(const u16x8*)(src + 2048);
#pragma unroll
    for (int j = 0; j < 8; j++)
      tile[k * 8 + j][sp] = (unsigned)r0[j] | ((unsigned)r1[j] << 16);
  }
  __syncthreads();
  {
    const int d = tid >> 2, m = tid & 3;
    u32x4 w0, w1;
#pragma unroll
    for (int i = 0; i < 4; i++) w0[i] = tile[d][m * 8 + i];
#pragma unroll
    for (int i = 0; i < 4; i++) w1[i] = tile[d][m * 8 + 4 + i];
    u16* dst = vt + (size_t)(bh * 128 + d0 + d) * 1024 + s0 + m * 16;
    *(u32x4*)dst = w0;
    *(u32x4*)(dst + 8) = w1;
  }
}

// ---------------------------------------------------------------- flash attention
// grid (T/64, H, B), 256 threads = 4 waves; wave w owns q-rows [tq*64+w*16, +16) over full S
__global__ __launch_bounds__(256) void attn_k(
    const u16* __restrict__ st,    // src_trans [B*S][2048] (key cols 0..1023)
    const u16* __restrict__ vt,    // [B*H][128][1024] (V^T)
    const u16* __restrict__ qb,    // tgt_trans [B*T][1024]
    const float* __restrict__ smask,
    u16* __restrict__ cat)         // [B*T][2048], writes cols 1024..2047
{
  const int tq = blockIdx.x, h = blockIdx.y, b = blockIdx.z;
  const int tid = threadIdx.x, wave = tid >> 6, lane = tid & 63;
  const int l = lane & 15, q = lane >> 4;

  __shared__ u16 Ks[64 * 128];     // K tile [s][d], chunk-swizzled: pos = c ^ (row&15)
  __shared__ u16 Vs[128 * 64];     // V^T tile [d][s], chunk-swizzled: pos = c ^ (row&7)
  __shared__ u16 Pl[4][16 * 72];   // per-wave P transpose scratch (padded, regular ds ops)

  const int qr0 = b * 512 + tq * 64 + wave * 16;
  bf16x8 aQ[4];
#pragma unroll
  for (int kk = 0; kk < 4; kk++)
    aQ[kk] = *(const bf16x8*)&qb[(size_t)(qr0 + l) * 1024 + h * 128 + kk * 32 + q * 8];

  const f32x4 zero = {0.f, 0.f, 0.f, 0.f};
  f32x4 o[8];
#pragma unroll
  for (int n = 0; n < 8; n++) o[n] = zero;
  float m_i[4], l_i[4];
#pragma unroll
  for (int r = 0; r < 4; r++) { m_i[r] = -3e38f; l_i[r] = 0.f; }

  const u16* kbase = st + (size_t)b * 1024 * 2048 + h * 128;
  const u16* vbase = vt + (size_t)(b * 8 + h) * 128 * 1024;
  const float* mbase = smask + b * 1024;
  const float scale = 0.08838834764831845f;  // 1/sqrt(128)

  const int krow = lane >> 4, kcp = lane & 15;   // K staging: 4 rows x 16 chunks per inst
  const int vrow = lane >> 3, vcp = lane & 7;    // V staging: 8 rows x 8 chunks per inst

  for (int s0 = 0; s0 < 1024; s0 += 64) {
    __syncthreads();
#pragma unroll
    for (int j = 0; j < 4; j++) {
      const int i = wave * 4 + j;
      const int kr = i * 4 + krow;
      g2l16(kbase + (size_t)(s0 + kr) * 2048 + (kcp ^ (kr & 15)) * 8, (const char*)Ks + i * 1024);
      const int vr = i * 8 + vrow;
      g2l16(vbase + (size_t)vr * 1024 + s0 + (vcp ^ (vr & 7)) * 8,    (const char*)Vs + i * 1024);
    }
    __syncthreads();

    // QK^T
    f32x4 s[4];
#pragma unroll
    for (int nt = 0; nt < 4; nt++) s[nt] = zero;
#pragma unroll
    for (int kk = 0; kk < 4; kk++) {
#pragma unroll
      for (int nt = 0; nt < 4; nt++) {
        bf16x8 bk = *(const bf16x8*)&Ks[(nt * 16 + l) * 128 + ((kk * 4 + q) ^ l) * 8];
        s[nt] = mfma_bf16(aQ[kk], bk, s[nt]);
      }
    }

    float msk[4];
#pragma unroll
    for (int nt = 0; nt < 4; nt++) msk[nt] = mbase[s0 + nt * 16 + l];

    // online softmax (wave-local; rows q*4+r, reduce over 16 l-lanes)
    float tm[4] = {-3e38f, -3e38f, -3e38f, -3e38f};
#pragma unroll
    for (int nt = 0; nt < 4; nt++) {
#pragma unroll
      for (int r = 0; r < 4; r++) {
        float v = s[nt][r] * scale;
        v = (msk[nt] == 0.f) ? -3e38f : v;
        s[nt][r] = v;
        tm[r] = fmaxf(tm[r], v);
      }
    }
#pragma unroll
    for (int off = 1; off < 16; off <<= 1)
#pragma unroll
      for (int r = 0; r < 4; r++) tm[r] = fmaxf(tm[r], __shfl_xor(tm[r], off));

    float alpha[4], ts[4];
#pragma unroll
    for (int r = 0; r < 4; r++) {
      const float mn = fmaxf(m_i[r], tm[r]);
      alpha[r] = __expf(m_i[r] - mn);
      m_i[r] = mn;
      ts[r] = 0.f;
    }
#pragma unroll
    for (int nt = 0; nt < 4; nt++) {
#pragma unroll
      for (int r = 0; r < 4; r++) {
        const float e = (msk[nt] == 0.f) ? 0.f : __expf(s[nt][r] - m_i[r]);
        ts[r] += e;
        Pl[wave][(q * 4 + r) * 72 + nt * 16 + l] = f2bf(e);
      }
    }
#pragma unroll
    for (int off = 1; off < 16; off <<= 1)
#pragma unroll
      for (int r = 0; r < 4; r++) ts[r] += __shfl_xor(ts[r], off);
#pragma unroll
    for (int r = 0; r < 4; r++) l_i[r] = l_i[r] * alpha[r] + ts[r];
#pragma unroll
    for (int n = 0; n < 8; n++)
#pragma unroll
      for (int r = 0; r < 4; r++) o[n][r] *= alpha[r];

    asm volatile("s_waitcnt lgkmcnt(0)" ::: "memory");  // P writes -> reads (wave-local)

    // PV: A from Pl (A-layout), B from swizzled Vs
#pragma unroll
    for (int k2 = 0; k2 < 2; k2++) {
      bf16x8 ap = *(const bf16x8*)&Pl[wave][l * 72 + k2 * 32 + q * 8];
#pragma unroll
      for (int n = 0; n < 8; n++) {
        bf16x8 bv = *(const bf16x8*)&Vs[(n * 16 + l) * 64 + (((k2 * 4 + q) ^ (l & 7))) * 8];
        o[n] = mfma_bf16(ap, bv, o[n]);
      }
    }
  }

  float inv[4];
#pragma unroll
  for (int r = 0; r < 4; r++) inv[r] = 1.f / l_i[r];
  u16* ob = cat + (size_t)(qr0 + q * 4) * 2048 + 1024 + h * 128 + l;
#pragma unroll
  for (int n = 0; n < 8; n++)
#pragma unroll
    for (int r = 0; r < 4; r++)
      ob[(size_t)r * 2048 + n * 16] = f2bf(o[n][r] * inv[r]);
}

// ---------------------------------------------------------------- launcher
extern "C" void kernel_launch(void* const* d_in, const int* in_sizes, int n_in,
                              void* d_out, int out_size, void* d_ws, size_t ws_size,
                              hipStream_t stream)
{
  (void)in_sizes; (void)n_in; (void)out_size; (void)ws_size;
  const float* src      = (const float*)d_in[0];
  const float* tgtf     = (const float*)d_in[1];
  const float* src_mask = (const float*)d_in[2];
  const float* tgt_mask = (const float*)d_in[3];
  const float* v_src = (const float*)d_in[4];
  const float* g_src = (const float*)d_in[5];
  const float* b_src = (const float*)d_in[6];
  const float* v_tgt = (const float*)d_in[7];
  const float* g_tgt = (const float*)d_in[8];
  const float* b_tgt = (const float*)d_in[9];
  const float* v_out = (const float*)d_in[10];
  const float* g_out = (const float*)d_in[11];
  const float* b_out = (const float*)d_in[12];

  char* w = (char*)d_ws;
  float* sumsq = (float*)w;
  size_t off = 256;
  u16* w_src = (u16*)(w + off); off += (size_t)2048 * 1024 * 2;
  u16* w_tgt = (u16*)(w + off); off += (size_t)1024 * 1024 * 2;
  u16* w_out = (u16*)(w + off); off += (size_t)1024 * 2048 * 2;
  u16* st    = (u16*)(w + off); off += (size_t)32768 * 2048 * 2;     // src_trans bf16
  u16* qb    = (u16*)(w + off); off += (size_t)16384 * 1024 * 2;     // tgt_trans bf16
  u16* srcb  = (u16*)(w + off);                                       // src bf16 (aliases vt)
  u16* vt    = (u16*)(w + off); off += (size_t)256 * 128 * 1024 * 2;  // V^T bf16 (after gemm1)
  u16* cat   = (u16*)(w + off); off += (size_t)16384 * 2048 * 2;      // [tgt | tgt_update] bf16

  hipMemsetAsync(sumsq, 0, 256, stream);
  sumsq_k<<<256, 256, 0, stream>>>(v_src, 2048 * 1024 / 4, sumsq + 0);
  sumsq_k<<<256, 256, 0, stream>>>(v_tgt, 1024 * 1024 / 4, sumsq + 1);
  sumsq_k<<<256, 256, 0, stream>>>(v_out, 1024 * 2048 / 4, sumsq + 2);
  wconv_k<<<2048, 256, 0, stream>>>(v_src, g_src, sumsq + 0, w_src, 2048 * 1024 / 4);
  wconv_k<<<1024, 256, 0, stream>>>(v_tgt, g_tgt, sumsq + 1, w_tgt, 1024 * 1024 / 4);
  wconv_k<<<2048, 256, 0, stream>>>(v_out, g_out, sumsq + 2, w_out, 1024 * 2048 / 4);
  cvt_k<<<32768, 256, 0, stream>>>(src, srcb);          // src -> bf16 (in vt buffer)
  catleft_k<<<16384, 256, 0, stream>>>(tgtf, cat);      // tgt -> bf16 into cat left half

  // src_trans = (src @ W_src^T + b_src) * src_mask   [32768 x 2048]
  gemm_bt<true, true><<<dim3(16, 256), 256, 0, stream>>>(
      srcb, w_src, b_src, src_mask, (void*)st, 1024, 1024, 2048);
  // tgt_trans = (tgt @ W_tgt^T + b_tgt) * tgt_mask   [16384 x 1024]  (A = cat left half, lda=2048)
  gemm_bt<true, true><<<dim3(8, 128), 256, 0, stream>>>(
      cat, w_tgt, b_tgt, tgt_mask, (void*)qb, 1024, 2048, 1024);
  // V^T (overwrites srcb alias — gemm1 is done with it)
  tpose_k<<<dim3(16, 2, 256), 256, 0, stream>>>(st, vt);
  // flash attention -> cat[:, 1024:]
  attn_k<<<dim3(8, 8, 32), 256, 0, stream>>>(st, vt, qb, src_mask, cat);
  // out = cat @ W_out^T + b_out   [16384 x 1024] f32
  gemm_bt<false, false><<<dim3(8, 128), 256, 0, stream>>>(
      cat, w_out, b_out, nullptr, d_out, 2048, 2048, 1024);
}

// Round 3
// 812.359 us; speedup vs baseline: 1.6097x; 1.1855x over previous
//
#include <hip/hip_runtime.h>
#include <hip/hip_bf16.h>
#include <math.h>

#define DEVI __device__ __forceinline__

typedef unsigned short u16;
typedef __attribute__((ext_vector_type(8))) __bf16 bf16x8;
typedef __attribute__((ext_vector_type(4))) float f32x4;
typedef __attribute__((ext_vector_type(8))) unsigned short u16x8;
typedef __attribute__((ext_vector_type(4))) unsigned short u16x4;

typedef __attribute__((address_space(1))) void gvoid;
typedef __attribute__((address_space(3))) void lvoid;

DEVI u16 f2bf(float f) {
  unsigned u = __builtin_bit_cast(unsigned, f);
  u += 0x7fffu + ((u >> 16) & 1u);   // RNE
  return (u16)(u >> 16);
}

DEVI f32x4 mfma_bf16(bf16x8 a, bf16x8 b, f32x4 c) {
  return __builtin_amdgcn_mfma_f32_16x16x32_bf16(a, b, c, 0, 0, 0);
}

DEVI void g2l16(const void* g, const void* l) {
  __builtin_amdgcn_global_load_lds((gvoid*)(size_t)g,
                                   (lvoid*)(unsigned)(size_t)l, 16, 0, 0);
}

// ---------------------------------------------------------------- fused small kernels
__global__ void sumsq3_k(const float* __restrict__ v0, const float* __restrict__ v1,
                         const float* __restrict__ v2, float* __restrict__ out)
{
  const int seg = blockIdx.x >> 7, wb = blockIdx.x & 127;
  const float* v = seg == 0 ? v0 : (seg == 1 ? v1 : v2);
  const int n4 = (seg == 1) ? 262144 : 524288;
  float s = 0.f;
  for (int i = wb * 256 + threadIdx.x; i < n4; i += 128 * 256) {
    f32x4 x = *(const f32x4*)(v + (size_t)i * 4);
    s += x.x * x.x + x.y * x.y + x.z * x.z + x.w * x.w;
  }
#pragma unroll
  for (int off = 32; off > 0; off >>= 1) s += __shfl_down(s, off);
  __shared__ float part[4];
  if ((threadIdx.x & 63) == 0) part[threadIdx.x >> 6] = s;
  __syncthreads();
  if (threadIdx.x == 0) atomicAdd(out + seg, part[0] + part[1] + part[2] + part[3]);
}

__global__ void wconv3_k(const float* __restrict__ v0, const float* __restrict__ v1,
                         const float* __restrict__ v2,
                         const float* __restrict__ g0, const float* __restrict__ g1,
                         const float* __restrict__ g2,
                         const float* __restrict__ ss,
                         u16* __restrict__ w0, u16* __restrict__ w1, u16* __restrict__ w2)
{
  const int i = blockIdx.x * 256 + threadIdx.x;  // f32x4 index over 1310720
  int seg, base;
  const float* v; u16* w;
  if (i < 524288)      { seg = 0; base = 0;      v = v0; w = w0; }
  else if (i < 786432) { seg = 1; base = 524288; v = v1; w = w1; }
  else                 { seg = 2; base = 786432; v = v2; w = w2; }
  const float* g = seg == 0 ? g0 : (seg == 1 ? g1 : g2);
  const float sc = g[0] / sqrtf(ss[seg]);
  const int j = i - base;
  f32x4 x = *(const f32x4*)(v + (size_t)j * 4);
  u16x4 o;
  o[0] = f2bf(x.x * sc); o[1] = f2bf(x.y * sc);
  o[2] = f2bf(x.z * sc); o[3] = f2bf(x.w * sc);
  *(u16x4*)(w + (size_t)j * 4) = o;
}

__global__ void cvt_k(const float* __restrict__ x, u16* __restrict__ y)
{
  const size_t i = (size_t)(blockIdx.x * blockDim.x + threadIdx.x) * 4;
  f32x4 v = *(const f32x4*)(x + i);
  u16x4 o;
  o[0] = f2bf(v.x); o[1] = f2bf(v.y); o[2] = f2bf(v.z); o[3] = f2bf(v.w);
  *(u16x4*)(y + i) = o;
}

__global__ void catleft_k(const float* __restrict__ tgt, u16* __restrict__ cat)
{
  const size_t e = (size_t)(blockIdx.x * blockDim.x + threadIdx.x) * 4;
  const int row = (int)(e >> 10), c = (int)(e & 1023);
  f32x4 x = *(const f32x4*)(tgt + e);
  u16x4 o;
  o[0] = f2bf(x.x); o[1] = f2bf(x.y); o[2] = f2bf(x.z); o[3] = f2bf(x.w);
  *(u16x4*)&cat[(size_t)row * 2048 + c] = o;
}

// ---------------------------------------------------------------- GEMM (C = A @ B^T + bias)
// BK=64, XOR chunk-swizzled LDS (conflict-free b128 reads). A [M][lda], B [N][K] bf16.
// OUT_MODE: 0 = f32 (ldc), 1 = bf16 (ldc), 2 = split: cols<1024 -> st[.][1024],
//           cols>=1024 -> transposed into vt[b*8+h][128][1024].
template<int OUT_MODE, bool HAS_MASK>
__global__ __launch_bounds__(256) void gemm_bt(
    const u16* __restrict__ Ap, const u16* __restrict__ Bp,
    const float* __restrict__ bias, const float* __restrict__ rowmask,
    void* __restrict__ Cp, u16* __restrict__ C2p, int K, int lda, int ldc)
{
  __shared__ u16 As[128 * 64];
  __shared__ u16 Bs[128 * 64];
  const int tid = threadIdx.x;
  const int wave = tid >> 6, lane = tid & 63;
  const int wm = (wave >> 1) * 64, wn = (wave & 1) * 64;
  const int l = lane & 15, q = lane >> 4;
  const int m0 = blockIdx.y * 128, n0 = blockIdx.x * 128;
  const int srow = lane >> 3;                      // row within 8-row staging inst
  const int scol = (((lane & 7) ^ srow)) * 8;      // swizzled global col (u16)

  const f32x4 zero = {0.f, 0.f, 0.f, 0.f};
  f32x4 acc[4][4];
#pragma unroll
  for (int i = 0; i < 4; i++)
#pragma unroll
    for (int j = 0; j < 4; j++) acc[i][j] = zero;

  for (int k0 = 0; k0 < K; k0 += 64) {
    __syncthreads();
#pragma unroll
    for (int j = 0; j < 4; j++) {
      const int i = wave * 4 + j;
      g2l16(Ap + (size_t)(m0 + i * 8 + srow) * lda + k0 + scol, (const char*)As + i * 1024);
      g2l16(Bp + (size_t)(n0 + i * 8 + srow) * K + k0 + scol,   (const char*)Bs + i * 1024);
    }
    __syncthreads();

#pragma unroll
    for (int ks = 0; ks < 2; ks++) {
      bf16x8 af[4], bfr[4];
      const int p = ((ks * 4 + q) ^ (l & 7)) * 8;
#pragma unroll
      for (int i = 0; i < 4; i++) af[i] = *(const bf16x8*)&As[(wm + i * 16 + l) * 64 + p];
#pragma unroll
      for (int j = 0; j < 4; j++) bfr[j] = *(const bf16x8*)&Bs[(wn + j * 16 + l) * 64 + p];
#pragma unroll
      for (int i = 0; i < 4; i++)
#pragma unroll
        for (int j = 0; j < 4; j++)
          acc[i][j] = mfma_bf16(af[i], bfr[j], acc[i][j]);
    }
  }

  float mk[4][4];
  if constexpr (HAS_MASK) {
#pragma unroll
    for (int i = 0; i < 4; i++)
#pragma unroll
      for (int r = 0; r < 4; r++)
        mk[i][r] = rowmask[m0 + wm + i * 16 + q * 4 + r];
  }
#pragma unroll
  for (int j = 0; j < 4; j++) {
    const int col = n0 + wn + j * 16 + l;
    const float bv = bias[col];
    if constexpr (OUT_MODE == 2) {
      if (col < 1024) {
#pragma unroll
        for (int i = 0; i < 4; i++)
#pragma unroll
          for (int r = 0; r < 4; r++) {
            float v = (acc[i][j][r] + bv) * mk[i][r];
            ((u16*)Cp)[(size_t)(m0 + wm + i * 16 + q * 4 + r) * 1024 + col] = f2bf(v);
          }
      } else {
        const int cv = col - 1024, h = cv >> 7, d = cv & 127;
#pragma unroll
        for (int i = 0; i < 4; i++) {
          const int m = m0 + wm + i * 16 + q * 4;
          u16x4 o;
#pragma unroll
          for (int r = 0; r < 4; r++) o[r] = f2bf((acc[i][j][r] + bv) * mk[i][r]);
          *(u16x4*)&C2p[((size_t)((m >> 10) * 8 + h) * 128 + d) * 1024 + (m & 1023)] = o;
        }
      }
    } else {
#pragma unroll
      for (int i = 0; i < 4; i++) {
#pragma unroll
        for (int r = 0; r < 4; r++) {
          float v = acc[i][j][r] + bv;
          if constexpr (HAS_MASK) v *= mk[i][r];
          const size_t off = (size_t)(m0 + wm + i * 16 + q * 4 + r) * ldc + col;
          if constexpr (OUT_MODE == 1) ((u16*)Cp)[off] = f2bf(v);
          else                         ((float*)Cp)[off] = v;
        }
      }
    }
  }
}

// ---------------------------------------------------------------- flash attention
// grid (T/128, H, B), 256 threads = 4 waves; wave owns 32 q-rows (two 16-row tiles)
__global__ __launch_bounds__(256) void attn_k(
    const u16* __restrict__ st,    // keys [B*S][1024]
    const u16* __restrict__ vt,    // [B*H][128][1024] (V^T)
    const u16* __restrict__ qb,    // tgt_trans [B*T][1024]
    const float* __restrict__ smask,
    u16* __restrict__ cat)         // [B*T][2048], writes cols 1024..2047
{
  const int tq = blockIdx.x, h = blockIdx.y, b = blockIdx.z;
  const int tid = threadIdx.x, wave = tid >> 6, lane = tid & 63;
  const int l = lane & 15, q = lane >> 4;

  __shared__ u16 Ks[64 * 128];     // [s][d], chunk-swizzled (16 chunks): pos = c ^ (row&15)
  __shared__ u16 Vs[128 * 64];     // [d][s], chunk-swizzled (8 chunks):  pos = c ^ (row&7)
  __shared__ u16 Pl[4][32 * 72];   // per-wave P scratch (padded rows)

  const int qr0 = b * 512 + tq * 128 + wave * 32;
  bf16x8 aQ[2][4];
#pragma unroll
  for (int m = 0; m < 2; m++)
#pragma unroll
    for (int kk = 0; kk < 4; kk++)
      aQ[m][kk] = *(const bf16x8*)&qb[(size_t)(qr0 + m * 16 + l) * 1024 + h * 128 + kk * 32 + q * 8];

  const f32x4 zero = {0.f, 0.f, 0.f, 0.f};
  f32x4 o[2][8];
#pragma unroll
  for (int m = 0; m < 2; m++)
#pragma unroll
    for (int n = 0; n < 8; n++) o[m][n] = zero;
  float m_i[2][4], l_i[2][4];
#pragma unroll
  for (int m = 0; m < 2; m++)
#pragma unroll
    for (int r = 0; r < 4; r++) { m_i[m][r] = -3e38f; l_i[m][r] = 0.f; }

  const u16* kbase = st + (size_t)b * 1024 * 1024 + h * 128;
  const u16* vbase = vt + (size_t)(b * 8 + h) * 128 * 1024;
  const float* mbase = smask + b * 1024;
  const float scale = 0.08838834764831845f;  // 1/sqrt(128)

  const int krow = lane >> 4, kcp = lane & 15;
  const int vrow = lane >> 3, vcp = lane & 7;

  for (int s0 = 0; s0 < 1024; s0 += 64) {
    __syncthreads();
#pragma unroll
    for (int j = 0; j < 4; j++) {
      const int i = wave * 4 + j;
      const int kr = i * 4 + krow;
      g2l16(kbase + (size_t)(s0 + kr) * 1024 + (kcp ^ (kr & 15)) * 8, (const char*)Ks + i * 1024);
      const int vr = i * 8 + vrow;
      g2l16(vbase + (size_t)vr * 1024 + s0 + (vcp ^ (vr & 7)) * 8,    (const char*)Vs + i * 1024);
    }
    __syncthreads();

    // QK^T — K-frags shared across both row-tiles
    f32x4 s[2][4];
#pragma unroll
    for (int m = 0; m < 2; m++)
#pragma unroll
      for (int nt = 0; nt < 4; nt++) s[m][nt] = zero;
#pragma unroll
    for (int kk = 0; kk < 4; kk++) {
#pragma unroll
      for (int nt = 0; nt < 4; nt++) {
        bf16x8 bk = *(const bf16x8*)&Ks[(nt * 16 + l) * 128 + ((kk * 4 + q) ^ l) * 8];
        s[0][nt] = mfma_bf16(aQ[0][kk], bk, s[0][nt]);
        s[1][nt] = mfma_bf16(aQ[1][kk], bk, s[1][nt]);
      }
    }

    float msk[4];
#pragma unroll
    for (int nt = 0; nt < 4; nt++) msk[nt] = mbase[s0 + nt * 16 + l];

#pragma unroll
    for (int m = 0; m < 2; m++) {
      float tm[4] = {-3e38f, -3e38f, -3e38f, -3e38f};
#pragma unroll
      for (int nt = 0; nt < 4; nt++) {
#pragma unroll
        for (int r = 0; r < 4; r++) {
          float v = s[m][nt][r] * scale;
          v = (msk[nt] == 0.f) ? -3e38f : v;
          s[m][nt][r] = v;
          tm[r] = fmaxf(tm[r], v);
        }
      }
#pragma unroll
      for (int off = 1; off < 16; off <<= 1)
#pragma unroll
        for (int r = 0; r < 4; r++) tm[r] = fmaxf(tm[r], __shfl_xor(tm[r], off));

      float alpha[4], ts[4];
#pragma unroll
      for (int r = 0; r < 4; r++) {
        const float mn = fmaxf(m_i[m][r], tm[r]);
        alpha[r] = __expf(m_i[m][r] - mn);
        m_i[m][r] = mn;
        ts[r] = 0.f;
      }
#pragma unroll
      for (int nt = 0; nt < 4; nt++) {
#pragma unroll
        for (int r = 0; r < 4; r++) {
          const float e = (msk[nt] == 0.f) ? 0.f : __expf(s[m][nt][r] - m_i[m][r]);
          ts[r] += e;
          Pl[wave][(m * 16 + q * 4 + r) * 72 + nt * 16 + l] = f2bf(e);
        }
      }
#pragma unroll
      for (int off = 1; off < 16; off <<= 1)
#pragma unroll
        for (int r = 0; r < 4; r++) ts[r] += __shfl_xor(ts[r], off);
#pragma unroll
      for (int r = 0; r < 4; r++) l_i[m][r] = l_i[m][r] * alpha[r] + ts[r];
#pragma unroll
      for (int n = 0; n < 8; n++)
#pragma unroll
        for (int r = 0; r < 4; r++) o[m][n][r] *= alpha[r];
    }

    asm volatile("s_waitcnt lgkmcnt(0)" ::: "memory");  // Pl writes -> reads (wave-local)

    // PV
#pragma unroll
    for (int k2 = 0; k2 < 2; k2++) {
      bf16x8 ap0 = *(const bf16x8*)&Pl[wave][l * 72 + k2 * 32 + q * 8];
      bf16x8 ap1 = *(const bf16x8*)&Pl[wave][(16 + l) * 72 + k2 * 32 + q * 8];
#pragma unroll
      for (int n = 0; n < 8; n++) {
        bf16x8 bv = *(const bf16x8*)&Vs[(n * 16 + l) * 64 + ((k2 * 4 + q) ^ (l & 7)) * 8];
        o[0][n] = mfma_bf16(ap0, bv, o[0][n]);
        o[1][n] = mfma_bf16(ap1, bv, o[1][n]);
      }
    }
  }

#pragma unroll
  for (int m = 0; m < 2; m++) {
    float inv[4];
#pragma unroll
    for (int r = 0; r < 4; r++) inv[r] = 1.f / l_i[m][r];
    u16* ob = cat + (size_t)(qr0 + m * 16 + q * 4) * 2048 + 1024 + h * 128 + l;
#pragma unroll
    for (int n = 0; n < 8; n++)
#pragma unroll
      for (int r = 0; r < 4; r++)
        ob[(size_t)r * 2048 + n * 16] = f2bf(o[m][n][r] * inv[r]);
  }
}

// ---------------------------------------------------------------- launcher
extern "C" void kernel_launch(void* const* d_in, const int* in_sizes, int n_in,
                              void* d_out, int out_size, void* d_ws, size_t ws_size,
                              hipStream_t stream)
{
  (void)in_sizes; (void)n_in; (void)out_size; (void)ws_size;
  const float* src      = (const float*)d_in[0];
  const float* tgtf     = (const float*)d_in[1];
  const float* src_mask = (const float*)d_in[2];
  const float* tgt_mask = (const float*)d_in[3];
  const float* v_src = (const float*)d_in[4];
  const float* g_src = (const float*)d_in[5];
  const float* b_src = (const float*)d_in[6];
  const float* v_tgt = (const float*)d_in[7];
  const float* g_tgt = (const float*)d_in[8];
  const float* b_tgt = (const float*)d_in[9];
  const float* v_out = (const float*)d_in[10];
  const float* g_out = (const float*)d_in[11];
  const float* b_out = (const float*)d_in[12];

  char* w = (char*)d_ws;
  float* sumsq = (float*)w;
  size_t off = 256;
  u16* w_src = (u16*)(w + off); off += (size_t)2048 * 1024 * 2;
  u16* w_tgt = (u16*)(w + off); off += (size_t)1024 * 1024 * 2;
  u16* w_out = (u16*)(w + off); off += (size_t)1024 * 2048 * 2;
  u16* st    = (u16*)(w + off); off += (size_t)32768 * 1024 * 2;     // keys only
  u16* qb    = (u16*)(w + off); off += (size_t)16384 * 1024 * 2;     // tgt_trans
  u16* vt    = (u16*)(w + off); off += (size_t)256 * 128 * 1024 * 2; // V^T
  u16* cat   = (u16*)(w + off); off += (size_t)16384 * 2048 * 2;     // [tgt | tgt_update]
  u16* srcb  = cat;  // src bf16 alias (consumed by gemm1 before catleft/attn overwrite)

  hipMemsetAsync(sumsq, 0, 256, stream);
  sumsq3_k<<<384, 256, 0, stream>>>(v_src, v_tgt, v_out, sumsq);
  wconv3_k<<<5120, 256, 0, stream>>>(v_src, v_tgt, v_out, g_src, g_tgt, g_out,
                                     sumsq, w_src, w_tgt, w_out);
  cvt_k<<<32768, 256, 0, stream>>>(src, srcb);

  // src_trans: keys -> st, values -> vt (transposed), both masked  [32768 x 2048]
  gemm_bt<2, true><<<dim3(16, 256), 256, 0, stream>>>(
      srcb, w_src, b_src, src_mask, (void*)st, vt, 1024, 1024, 0);
  catleft_k<<<16384, 256, 0, stream>>>(tgtf, cat);
  // tgt_trans = (tgt @ W_tgt^T + b_tgt) * tgt_mask   [16384 x 1024]
  gemm_bt<1, true><<<dim3(8, 128), 256, 0, stream>>>(
      cat, w_tgt, b_tgt, tgt_mask, (void*)qb, nullptr, 1024, 2048, 1024);
  // flash attention -> cat[:, 1024:]
  attn_k<<<dim3(4, 8, 32), 256, 0, stream>>>(st, vt, qb, src_mask, cat);
  // out = cat @ W_out^T + b_out   [16384 x 1024] f32
  gemm_bt<0, false><<<dim3(8, 128), 256, 0, stream>>>(
      cat, w_out, b_out, nullptr, d_out, nullptr, 2048, 2048, 1024);
}